// Round 3
// baseline (841.711 us; speedup 1.0000x reference)
//
#include <hip/hip_runtime.h>
#include <hip/hip_bf16.h>

// VGAE on MI355X. N=10000, E=320000, F_IN=128, HID=32, all fp32.
// Round 2 (resubmit): replace 20.5M fp32 atomics with a per-launch CSR build
// (histogram + scan + scatter: only 320K int atomics) and two atomic-free
// gathers. Decode: float4 LDS reads + nontemporal streaming stores.

#define N_NODES 10000
#define N_EDGES 320000
#define F_IN 128
#define HID 32

// ---------------- Layer-1 input GEMM: xws = x@W1s + b1, xwn = x@W1n -------
// 32 nodes per 256-thread block; each thread computes 4 nodes x 1 column.
__global__ __launch_bounds__(256) void k_gemm_in(
    const float* __restrict__ x, const float* __restrict__ Ws,
    const float* __restrict__ Wn, const float* __restrict__ b,
    float* __restrict__ outS, float* __restrict__ outN) {
  __shared__ float sWs[F_IN * HID];   // 16 KB
  __shared__ float sWn[F_IN * HID];   // 16 KB
  __shared__ float sx[32 * F_IN];     // 16 KB
  const int t = threadIdx.x;
  const int node0 = blockIdx.x * 32;
  #pragma unroll
  for (int i = t * 4; i < F_IN * HID; i += 1024) {
    *(float4*)&sWs[i] = *(const float4*)&Ws[i];
    *(float4*)&sWn[i] = *(const float4*)&Wn[i];
  }
  // 32 rows x 128 floats = 4096; 4 float4 per thread
  #pragma unroll
  for (int i = t * 4; i < 32 * F_IN; i += 1024) {
    const int r = i >> 7, k = i & 127;
    const int gr = node0 + r;
    float4 v = make_float4(0.f, 0.f, 0.f, 0.f);
    if (gr < N_NODES) v = *(const float4*)&x[gr * F_IN + k];
    *(float4*)&sx[i] = v;
  }
  __syncthreads();
  const int c = t & 31, g = t >> 5;  // column, row-group 0..7
  float accS[4] = {0.f, 0.f, 0.f, 0.f};
  float accN[4] = {0.f, 0.f, 0.f, 0.f};
  #pragma unroll 4
  for (int k = 0; k < F_IN; ++k) {
    const float ws = sWs[k * HID + c];
    const float wn = sWn[k * HID + c];
    #pragma unroll
    for (int m = 0; m < 4; ++m) {
      const float a = sx[(g + 8 * m) * F_IN + k];
      accS[m] += a * ws;
      accN[m] += a * wn;
    }
  }
  const float bc = b[c];
  #pragma unroll
  for (int m = 0; m < 4; ++m) {
    const int node = node0 + g + 8 * m;
    if (node < N_NODES) {
      outS[node * HID + c] = accS[m] + bc;
      outN[node * HID + c] = accN[m];
    }
  }
}

// ---------------- CSR build ----------------------------------------------
__global__ __launch_bounds__(256) void k_degree(const int* __restrict__ dst,
                                                int* __restrict__ degi) {
  const int e = blockIdx.x * 256 + threadIdx.x;
  if (e < N_EDGES) atomicAdd(&degi[dst[e]], 1);
}

// single block: exclusive scan of degi -> off, cursor; rdeg = 1/max(deg,1)
__global__ __launch_bounds__(256) void k_scan(const int* __restrict__ degi,
                                              int* __restrict__ off,
                                              int* __restrict__ cursor,
                                              float* __restrict__ rdeg) {
  __shared__ int part[256];
  const int t = threadIdx.x;
  const int PER = (N_NODES + 255) / 256;  // 40
  const int base = t * PER;
  int sum = 0;
  for (int i = 0; i < PER; ++i) {
    const int idx = base + i;
    if (idx < N_NODES) sum += degi[idx];
  }
  part[t] = sum;
  __syncthreads();
  for (int d = 1; d < 256; d <<= 1) {
    const int v = (t >= d) ? part[t - d] : 0;
    __syncthreads();
    part[t] += v;
    __syncthreads();
  }
  int run = (t == 0) ? 0 : part[t - 1];
  for (int i = 0; i < PER; ++i) {
    const int idx = base + i;
    if (idx < N_NODES) {
      const int d = degi[idx];
      off[idx] = run;
      cursor[idx] = run;
      rdeg[idx] = 1.0f / (float)(d > 1 ? d : 1);
      run += d;
    }
  }
  if (t == 255) off[N_NODES] = run;
}

__global__ __launch_bounds__(256) void k_scatter(const int* __restrict__ src,
                                                 const int* __restrict__ dst,
                                                 int* __restrict__ cursor,
                                                 int* __restrict__ esrc) {
  const int e = blockIdx.x * 256 + threadIdx.x;
  if (e >= N_EDGES) return;
  const int pos = atomicAdd(&cursor[dst[e]], 1);
  esrc[pos] = src[e];
}

// ---------------- Gather-mean (atomic-free) -------------------------------
// Half-wave (32 lanes, k = lane) per node; serial loop over in-edges.
// RELU_ADD: out = relu(addend + mean) (layer-1 finish fused).
template <bool RELU_ADD>
__global__ __launch_bounds__(256) void k_gather(
    const float* __restrict__ feat, const int* __restrict__ off,
    const int* __restrict__ esrc, const float* __restrict__ rdeg,
    const float* __restrict__ addend, float* __restrict__ out) {
  const int t = threadIdx.x;
  const int node = blockIdx.x * 8 + (t >> 5);
  const int k = t & 31;
  if (node >= N_NODES) return;
  const int j0 = off[node], j1 = off[node + 1];
  float acc = 0.f;
  int j = j0;
  for (; j + 3 < j1; j += 4) {
    const int s0 = esrc[j], s1 = esrc[j + 1], s2 = esrc[j + 2],
              s3 = esrc[j + 3];
    acc += feat[s0 * HID + k];
    acc += feat[s1 * HID + k];
    acc += feat[s2 * HID + k];
    acc += feat[s3 * HID + k];
  }
  for (; j < j1; ++j) acc += feat[esrc[j] * HID + k];
  float v = acc * rdeg[node];
  if (RELU_ADD) {
    v += addend[node * HID + k];
    v = v > 0.f ? v : 0.f;
  }
  out[node * HID + k] = v;
}

// ---------------- Layer 2 (mu & logstd) + reparameterize ------------------
__global__ __launch_bounds__(256) void k_layer2(
    const float* __restrict__ h, const float* __restrict__ hn,
    const float* __restrict__ eps, const float* __restrict__ Wms,
    const float* __restrict__ Wmn, const float* __restrict__ bm,
    const float* __restrict__ Wls, const float* __restrict__ Wln,
    const float* __restrict__ bl, float* __restrict__ mu_out,
    float* __restrict__ ls_out, float* __restrict__ z) {
  __shared__ float sMs[HID * HID], sMn[HID * HID];
  __shared__ float sLs[HID * HID], sLn[HID * HID];
  __shared__ float sh[8 * HID], shn[8 * HID];
  const int t = threadIdx.x;
  {
    const int i = t * 4;
    *(float4*)&sMs[i] = *(const float4*)&Wms[i];
    *(float4*)&sMn[i] = *(const float4*)&Wmn[i];
    *(float4*)&sLs[i] = *(const float4*)&Wls[i];
    *(float4*)&sLn[i] = *(const float4*)&Wln[i];
  }
  const int node0 = blockIdx.x * 8;
  sh[t] = h[node0 * HID + t];
  shn[t] = hn[node0 * HID + t];
  __syncthreads();
  const int r = t >> 5, c = t & 31;
  const int node = node0 + r;
  float mu = 0.f, ls = 0.f;
  #pragma unroll 8
  for (int k = 0; k < HID; ++k) {
    const float a = sh[r * HID + k];
    const float an = shn[r * HID + k];
    mu += a * sMs[k * HID + c] + an * sMn[k * HID + c];
    ls += a * sLs[k * HID + c] + an * sLn[k * HID + c];
  }
  if (node < N_NODES) {
    mu += bm[c];
    ls += bl[c];
    const int idx = node * HID + c;
    mu_out[idx] = mu;
    ls_out[idx] = ls;
    z[idx] = mu + eps[idx] * __expf(ls);
  }
}

// ---------------- Decoder: adj = sigmoid(z z^T) ---------------------------
// 128x128 tile / 256 threads; 8x8 outputs per thread; float4 LDS reads.
__global__ __launch_bounds__(256) void k_decode(const float* __restrict__ z,
                                                float* __restrict__ adj) {
  __shared__ float za[128][36];
  __shared__ float zb[128][36];
  const int r0 = blockIdx.y * 128;
  const int c0 = blockIdx.x * 128;
  const int t = threadIdx.x;
  for (int i = t; i < 128 * 8; i += 256) {
    const int row = i >> 3, k0 = (i & 7) << 2;
    const int gr = r0 + row;
    const int gc = c0 + row;
    float4 va = make_float4(0.f, 0.f, 0.f, 0.f);
    float4 vb = make_float4(0.f, 0.f, 0.f, 0.f);
    if (gr < N_NODES) va = *(const float4*)&z[gr * HID + k0];
    if (gc < N_NODES) vb = *(const float4*)&z[gc * HID + k0];
    *(float4*)&za[row][k0] = va;
    *(float4*)&zb[row][k0] = vb;
  }
  __syncthreads();
  const int tx = t & 15, ty = t >> 4;
  float acc[8][8];
  #pragma unroll
  for (int i = 0; i < 8; ++i)
    #pragma unroll
    for (int j = 0; j < 8; ++j) acc[i][j] = 0.f;

  #pragma unroll
  for (int k0 = 0; k0 < HID; k0 += 4) {
    float4 a4[8], b4[8];
    #pragma unroll
    for (int i = 0; i < 8; ++i) a4[i] = *(const float4*)&za[ty + i * 16][k0];
    #pragma unroll
    for (int j = 0; j < 8; ++j) b4[j] = *(const float4*)&zb[tx + j * 16][k0];
    #pragma unroll
    for (int i = 0; i < 8; ++i)
      #pragma unroll
      for (int j = 0; j < 8; ++j)
        acc[i][j] += a4[i].x * b4[j].x + a4[i].y * b4[j].y +
                     a4[i].z * b4[j].z + a4[i].w * b4[j].w;
  }

  #pragma unroll
  for (int i = 0; i < 8; ++i) {
    const int r = r0 + ty + i * 16;
    if (r >= N_NODES) continue;
    float* rowp = adj + (size_t)r * N_NODES;
    #pragma unroll
    for (int j = 0; j < 8; ++j) {
      const int c = c0 + tx + j * 16;
      if (c < N_NODES) {
        const float v = acc[i][j];
        const float s = __builtin_amdgcn_rcpf(1.f + __expf(-v));
        __builtin_nontemporal_store(s, &rowp[c]);
      }
    }
  }
}

extern "C" void kernel_launch(void* const* d_in, const int* in_sizes, int n_in,
                              void* d_out, int out_size, void* d_ws,
                              size_t ws_size, hipStream_t stream) {
  const float* x   = (const float*)d_in[0];
  const int* src   = (const int*)d_in[1];
  const int* dst   = (const int*)d_in[2];
  const float* eps = (const float*)d_in[3];
  const float* W1s = (const float*)d_in[4];
  const float* W1n = (const float*)d_in[5];
  const float* b1  = (const float*)d_in[6];
  const float* Wms = (const float*)d_in[7];
  const float* Wmn = (const float*)d_in[8];
  const float* bm  = (const float*)d_in[9];
  const float* Wls = (const float*)d_in[10];
  const float* Wln = (const float*)d_in[11];
  const float* bl  = (const float*)d_in[12];

  float* out = (float*)d_out;
  float* adj = out;                                    // [N, N]
  float* mu_out = out + (size_t)N_NODES * N_NODES;     // [N, HID]
  float* ls_out = mu_out + (size_t)N_NODES * HID;      // [N, HID]

  // workspace layout
  char* wsb = (char*)d_ws;
  int* degi   = (int*)wsb;                          // N (zeroed)
  int* off    = degi + N_NODES;                     // N+1
  int* cursor = off + N_NODES + 1;                  // N
  int* esrc   = cursor + N_NODES;                   // E
  float* rdeg = (float*)(esrc + N_EDGES);           // N
  float* xws  = rdeg + N_NODES;                     // N*HID
  float* xwn  = xws + N_NODES * HID;                // N*HID
  float* h    = xwn + N_NODES * HID;                // N*HID
  float* hn   = h + N_NODES * HID;                  // N*HID
  float* z    = hn + N_NODES * HID;                 // N*HID
  (void)ws_size; (void)in_sizes; (void)n_in; (void)out_size;

  // zero only the degree histogram (40 KB)
  hipMemsetAsync(degi, 0, (size_t)N_NODES * sizeof(int), stream);

  // layer-1 projections (independent of CSR build)
  k_gemm_in<<<dim3((N_NODES + 31) / 32), dim3(256), 0, stream>>>(
      x, W1s, W1n, b1, xws, xwn);
  // CSR build (reused by both layers)
  k_degree<<<dim3((N_EDGES + 255) / 256), dim3(256), 0, stream>>>(dst, degi);
  k_scan<<<dim3(1), dim3(256), 0, stream>>>(degi, off, cursor, rdeg);
  k_scatter<<<dim3((N_EDGES + 255) / 256), dim3(256), 0, stream>>>(
      src, dst, cursor, esrc);
  // layer 1: h = relu(xws + mean_gather(xwn))
  k_gather<true><<<dim3((N_NODES + 7) / 8), dim3(256), 0, stream>>>(
      xwn, off, esrc, rdeg, xws, h);
  // layer 2 aggregation: hn = mean_gather(h)
  k_gather<false><<<dim3((N_NODES + 7) / 8), dim3(256), 0, stream>>>(
      h, off, esrc, rdeg, nullptr, hn);
  // layer 2 + reparameterize
  k_layer2<<<dim3((N_NODES + 7) / 8), dim3(256), 0, stream>>>(
      h, hn, eps, Wms, Wmn, bm, Wls, Wln, bl, mu_out, ls_out, z);
  // decode
  dim3 dgrid((N_NODES + 127) / 128, (N_NODES + 127) / 128);
  k_decode<<<dgrid, dim3(256), 0, stream>>>(z, adj);
}

// Round 6
// 578.259 us; speedup vs baseline: 1.4556x; 1.4556x over previous
//
#include <hip/hip_runtime.h>
#include <hip/hip_bf16.h>

// VGAE on MI355X. N=10000, E=320000, F_IN=128, HID=32, all fp32.
// Round 4 (resubmit x2): atomic aggregation (measured-fast in round 1;
// CSR build was a ~70us regression). Decode rebuilt for occupancy:
// 64x64 tile, 4x4 per thread, scalar LDS reads (~50 VGPR vs 256),
// plain stores (no nontemporal -> L2 write-combining), XCD-bijective swizzle.

#define N_NODES 10000
#define N_EDGES 320000
#define F_IN 128
#define HID 32

// ---------------- Layer-1 input GEMM: xws = x@W1s + b1, xwn = x@W1n -------
__global__ __launch_bounds__(256) void k_gemm_in(
    const float* __restrict__ x, const float* __restrict__ Ws,
    const float* __restrict__ Wn, const float* __restrict__ b,
    float* __restrict__ outS, float* __restrict__ outN) {
  __shared__ float sWs[F_IN * HID];   // 16 KB
  __shared__ float sWn[F_IN * HID];   // 16 KB
  __shared__ float sx[32 * F_IN];     // 16 KB
  const int t = threadIdx.x;
  const int node0 = blockIdx.x * 32;
  #pragma unroll
  for (int i = t * 4; i < F_IN * HID; i += 1024) {
    *(float4*)&sWs[i] = *(const float4*)&Ws[i];
    *(float4*)&sWn[i] = *(const float4*)&Wn[i];
  }
  #pragma unroll
  for (int i = t * 4; i < 32 * F_IN; i += 1024) {
    const int r = i >> 7, k = i & 127;
    const int gr = node0 + r;
    float4 v = make_float4(0.f, 0.f, 0.f, 0.f);
    if (gr < N_NODES) v = *(const float4*)&x[gr * F_IN + k];
    *(float4*)&sx[i] = v;
  }
  __syncthreads();
  const int c = t & 31, g = t >> 5;  // column, row-group 0..7
  float accS[4] = {0.f, 0.f, 0.f, 0.f};
  float accN[4] = {0.f, 0.f, 0.f, 0.f};
  #pragma unroll 4
  for (int k = 0; k < F_IN; ++k) {
    const float ws = sWs[k * HID + c];
    const float wn = sWn[k * HID + c];
    #pragma unroll
    for (int m = 0; m < 4; ++m) {
      const float a = sx[(g + 8 * m) * F_IN + k];
      accS[m] += a * ws;
      accN[m] += a * wn;
    }
  }
  const float bc = b[c];
  #pragma unroll
  for (int m = 0; m < 4; ++m) {
    const int node = node0 + g + 8 * m;
    if (node < N_NODES) {
      outS[node * HID + c] = accS[m] + bc;
      outN[node * HID + c] = accN[m];
    }
  }
}

// ---------------- Edge aggregation: agg[dst] += feat[src] (atomics) -------
__global__ __launch_bounds__(256) void k_aggregate(
    const float* __restrict__ feat, const int* __restrict__ src,
    const int* __restrict__ dst, float* __restrict__ agg,
    float* __restrict__ deg) {
  const int tid = blockIdx.x * 256 + threadIdx.x;
  const int e = tid >> 5;
  const int k = tid & 31;
  if (e >= N_EDGES) return;
  const int s = src[e];
  const int d = dst[e];
  atomicAdd(&agg[d * HID + k], feat[s * HID + k]);
  if (deg != nullptr && k == 0) atomicAdd(&deg[d], 1.0f);
}

// ---------------- Layer-1 finish: h = relu(xws + agg/deg) -----------------
__global__ __launch_bounds__(256) void k_layer1_finish(
    const float* __restrict__ xws, const float* __restrict__ agg,
    const float* __restrict__ deg, float* __restrict__ h) {
  const int i = blockIdx.x * 256 + threadIdx.x;
  if (i >= N_NODES * HID) return;
  const int node = i >> 5;
  float dv = deg[node];
  dv = dv > 1.f ? dv : 1.f;
  const float v = xws[i] + agg[i] / dv;
  h[i] = v > 0.f ? v : 0.f;
}

// ---------------- Layer 2 (mu & logstd) + reparameterize ------------------
__global__ __launch_bounds__(256) void k_layer2(
    const float* __restrict__ h, const float* __restrict__ aggh,
    const float* __restrict__ deg, const float* __restrict__ eps,
    const float* __restrict__ Wms, const float* __restrict__ Wmn,
    const float* __restrict__ bm, const float* __restrict__ Wls,
    const float* __restrict__ Wln, const float* __restrict__ bl,
    float* __restrict__ mu_out, float* __restrict__ ls_out,
    float* __restrict__ z) {
  __shared__ float sMs[HID * HID], sMn[HID * HID];
  __shared__ float sLs[HID * HID], sLn[HID * HID];
  __shared__ float sh[8 * HID], shn[8 * HID];
  const int t = threadIdx.x;
  {
    const int i = t * 4;
    *(float4*)&sMs[i] = *(const float4*)&Wms[i];
    *(float4*)&sMn[i] = *(const float4*)&Wmn[i];
    *(float4*)&sLs[i] = *(const float4*)&Wls[i];
    *(float4*)&sLn[i] = *(const float4*)&Wln[i];
  }
  const int node0 = blockIdx.x * 8;
  const int lr = t >> 5;
  const int gnode_ld = node0 + lr;
  if (gnode_ld < N_NODES) {
    float dv = deg[gnode_ld];
    dv = dv > 1.f ? dv : 1.f;
    sh[t] = h[node0 * HID + t];
    shn[t] = aggh[node0 * HID + t] / dv;
  } else {
    sh[t] = 0.f;
    shn[t] = 0.f;
  }
  __syncthreads();
  const int r = t >> 5, c = t & 31;
  const int node = node0 + r;
  float mu = 0.f, ls = 0.f;
  #pragma unroll 8
  for (int k = 0; k < HID; ++k) {
    const float a = sh[r * HID + k];
    const float an = shn[r * HID + k];
    mu += a * sMs[k * HID + c] + an * sMn[k * HID + c];
    ls += a * sLs[k * HID + c] + an * sLn[k * HID + c];
  }
  if (node < N_NODES) {
    mu += bm[c];
    ls += bl[c];
    const int idx = node * HID + c;
    mu_out[idx] = mu;
    ls_out[idx] = ls;
    z[idx] = mu + eps[idx] * __expf(ls);
  }
}

// ---------------- Decoder: adj = sigmoid(z z^T) ---------------------------
// 64x64 tile / 256 threads; 4x4 per thread (acc=16 regs -> high occupancy).
// 18KB LDS -> 8 blocks/CU. Scalar LDS reads (a: broadcast, b: 2-way = free).
// XCD-bijective swizzle, col-tile fastest: adjacent col tiles share the
// row-panel (za reuse) and the partially-written cache lines in one L2.
#define NT_COL 157                     // ceil(10000/64)
#define NWG (NT_COL * NT_COL)          // 24649
#define NWG_Q (NWG / 8)                // 3081
#define NWG_R (NWG % 8)                // 1
__global__ __launch_bounds__(256, 4) void k_decode(const float* __restrict__ z,
                                                   float* __restrict__ adj) {
  __shared__ float za[64][36];
  __shared__ float zb[64][36];
  const int bid = blockIdx.x;
  const int xcd = bid & 7, idx = bid >> 3;
  const int wg = (xcd < NWG_R) ? xcd * (NWG_Q + 1) + idx
                               : NWG_R * (NWG_Q + 1) + (xcd - NWG_R) * NWG_Q + idx;
  const int rowt = wg / NT_COL, colt = wg % NT_COL;
  const int r0 = rowt * 64;
  const int c0 = colt * 64;
  const int t = threadIdx.x;
  // stage 64 rows x 32 floats for both sides: 512 float4, 2 per thread
  #pragma unroll
  for (int i = t; i < 512; i += 256) {
    const int row = i >> 3, k4 = (i & 7) << 2;
    const int gr = r0 + row;
    const int gc = c0 + row;
    float4 va = make_float4(0.f, 0.f, 0.f, 0.f);
    float4 vb = make_float4(0.f, 0.f, 0.f, 0.f);
    if (gr < N_NODES) va = *(const float4*)&z[gr * HID + k4];
    if (gc < N_NODES) vb = *(const float4*)&z[gc * HID + k4];
    *(float4*)&za[row][k4] = va;
    *(float4*)&zb[row][k4] = vb;
  }
  __syncthreads();
  const int tx = t & 15, ty = t >> 4;
  float acc[4][4];
  #pragma unroll
  for (int i = 0; i < 4; ++i)
    #pragma unroll
    for (int j = 0; j < 4; ++j) acc[i][j] = 0.f;

  #pragma unroll 4
  for (int k = 0; k < HID; ++k) {
    float a[4], b[4];
    #pragma unroll
    for (int i = 0; i < 4; ++i) a[i] = za[ty + i * 16][k];
    #pragma unroll
    for (int j = 0; j < 4; ++j) b[j] = zb[tx + j * 16][k];
    #pragma unroll
    for (int i = 0; i < 4; ++i)
      #pragma unroll
      for (int j = 0; j < 4; ++j) acc[i][j] += a[i] * b[j];
  }

  #pragma unroll
  for (int i = 0; i < 4; ++i) {
    const int r = r0 + ty + i * 16;
    if (r >= N_NODES) continue;
    float* rowp = adj + (size_t)r * N_NODES;
    #pragma unroll
    for (int j = 0; j < 4; ++j) {
      const int c = c0 + tx + j * 16;
      if (c < N_NODES) {
        const float v = acc[i][j];
        rowp[c] = __builtin_amdgcn_rcpf(1.f + __expf(-v));
      }
    }
  }
}

extern "C" void kernel_launch(void* const* d_in, const int* in_sizes, int n_in,
                              void* d_out, int out_size, void* d_ws,
                              size_t ws_size, hipStream_t stream) {
  const float* x   = (const float*)d_in[0];
  const int* src   = (const int*)d_in[1];
  const int* dst   = (const int*)d_in[2];
  const float* eps = (const float*)d_in[3];
  const float* W1s = (const float*)d_in[4];
  const float* W1n = (const float*)d_in[5];
  const float* b1  = (const float*)d_in[6];
  const float* Wms = (const float*)d_in[7];
  const float* Wmn = (const float*)d_in[8];
  const float* bm  = (const float*)d_in[9];
  const float* Wls = (const float*)d_in[10];
  const float* Wln = (const float*)d_in[11];
  const float* bl  = (const float*)d_in[12];

  float* out = (float*)d_out;
  float* adj = out;                                    // [N, N]
  float* mu_out = out + (size_t)N_NODES * N_NODES;     // [N, HID]
  float* ls_out = mu_out + (size_t)N_NODES * HID;      // [N, HID]

  // workspace layout (floats). zeroed region first (deg+agg+aggh).
  float* ws = (float*)d_ws;
  float* deg  = ws;                       // N
  float* agg  = ws + N_NODES;             // N*HID
  float* aggh = agg + N_NODES * HID;      // N*HID
  float* xws  = aggh + N_NODES * HID;     // N*HID
  float* xwn  = xws + N_NODES * HID;      // N*HID
  float* h    = xwn + N_NODES * HID;      // N*HID
  float* z    = h + N_NODES * HID;        // N*HID
  (void)ws_size; (void)in_sizes; (void)n_in; (void)out_size;

  // zero deg + agg + aggh (2.6 MB)
  hipMemsetAsync(ws, 0, (size_t)(N_NODES + 2 * N_NODES * HID) * sizeof(float),
                 stream);

  // layer-1 projections
  k_gemm_in<<<dim3((N_NODES + 31) / 32), dim3(256), 0, stream>>>(
      x, W1s, W1n, b1, xws, xwn);
  // aggregate projected neighbors + degree (atomics; ~20us measured-class)
  k_aggregate<<<dim3((N_EDGES * HID) / 256), dim3(256), 0, stream>>>(
      xwn, src, dst, agg, deg);
  // h = relu(xws + agg/deg)
  k_layer1_finish<<<dim3((N_NODES * HID) / 256), dim3(256), 0, stream>>>(
      xws, agg, deg, h);
  // aggregate h
  k_aggregate<<<dim3((N_EDGES * HID) / 256), dim3(256), 0, stream>>>(
      h, src, dst, aggh, nullptr);
  // layer 2 + reparameterize
  k_layer2<<<dim3((N_NODES + 7) / 8), dim3(256), 0, stream>>>(
      h, aggh, deg, eps, Wms, Wmn, bm, Wls, Wln, bl, mu_out, ls_out, z);
  // decode (1D grid, XCD-swizzled)
  k_decode<<<dim3(NWG), dim3(256), 0, stream>>>(z, adj);
}

// Round 7
// 555.943 us; speedup vs baseline: 1.5140x; 1.0401x over previous
//
#include <hip/hip_runtime.h>
#include <hip/hip_bf16.h>

// VGAE on MI355X. N=10000, E=320000, F_IN=128, HID=32.
// Round 7: decode via bf16 MFMA with hi/lo split-precision.
//   z = zh + zl (bf16 truncate + exact fp32 residual -> bf16)
//   z.z' = zh.zh' + zh.zl' + zl.zh'  (zl.zl' ~ 2^-16 rel, dropped)
// 3x mfma_f32_16x16x32_bf16 per 16x16 tile replaces the fp32 VALU
// inner product (decode was LDS/VALU-issue-bound at ~180us; write floor
// is 64us). Rest of the pipeline unchanged from round 6 (measured ~73us).

#define N_NODES 10000
#define N_EDGES 320000
#define F_IN 128
#define HID 32

typedef short bf16x8 __attribute__((ext_vector_type(8)));
typedef float f32x4 __attribute__((ext_vector_type(4)));

// ---------------- Layer-1 input GEMM: xws = x@W1s + b1, xwn = x@W1n -------
__global__ __launch_bounds__(256) void k_gemm_in(
    const float* __restrict__ x, const float* __restrict__ Ws,
    const float* __restrict__ Wn, const float* __restrict__ b,
    float* __restrict__ outS, float* __restrict__ outN) {
  __shared__ float sWs[F_IN * HID];   // 16 KB
  __shared__ float sWn[F_IN * HID];   // 16 KB
  __shared__ float sx[32 * F_IN];     // 16 KB
  const int t = threadIdx.x;
  const int node0 = blockIdx.x * 32;
  #pragma unroll
  for (int i = t * 4; i < F_IN * HID; i += 1024) {
    *(float4*)&sWs[i] = *(const float4*)&Ws[i];
    *(float4*)&sWn[i] = *(const float4*)&Wn[i];
  }
  #pragma unroll
  for (int i = t * 4; i < 32 * F_IN; i += 1024) {
    const int r = i >> 7, k = i & 127;
    const int gr = node0 + r;
    float4 v = make_float4(0.f, 0.f, 0.f, 0.f);
    if (gr < N_NODES) v = *(const float4*)&x[gr * F_IN + k];
    *(float4*)&sx[i] = v;
  }
  __syncthreads();
  const int c = t & 31, g = t >> 5;
  float accS[4] = {0.f, 0.f, 0.f, 0.f};
  float accN[4] = {0.f, 0.f, 0.f, 0.f};
  #pragma unroll 4
  for (int k = 0; k < F_IN; ++k) {
    const float ws = sWs[k * HID + c];
    const float wn = sWn[k * HID + c];
    #pragma unroll
    for (int m = 0; m < 4; ++m) {
      const float a = sx[(g + 8 * m) * F_IN + k];
      accS[m] += a * ws;
      accN[m] += a * wn;
    }
  }
  const float bc = b[c];
  #pragma unroll
  for (int m = 0; m < 4; ++m) {
    const int node = node0 + g + 8 * m;
    if (node < N_NODES) {
      outS[node * HID + c] = accS[m] + bc;
      outN[node * HID + c] = accN[m];
    }
  }
}

// ---------------- Edge aggregation: agg[dst] += feat[src] (atomics) -------
__global__ __launch_bounds__(256) void k_aggregate(
    const float* __restrict__ feat, const int* __restrict__ src,
    const int* __restrict__ dst, float* __restrict__ agg,
    float* __restrict__ deg) {
  const int tid = blockIdx.x * 256 + threadIdx.x;
  const int e = tid >> 5;
  const int k = tid & 31;
  if (e >= N_EDGES) return;
  const int s = src[e];
  const int d = dst[e];
  atomicAdd(&agg[d * HID + k], feat[s * HID + k]);
  if (deg != nullptr && k == 0) atomicAdd(&deg[d], 1.0f);
}

// ---------------- Layer-1 finish: h = relu(xws + agg/deg) -----------------
__global__ __launch_bounds__(256) void k_layer1_finish(
    const float* __restrict__ xws, const float* __restrict__ agg,
    const float* __restrict__ deg, float* __restrict__ h) {
  const int i = blockIdx.x * 256 + threadIdx.x;
  if (i >= N_NODES * HID) return;
  const int node = i >> 5;
  float dv = deg[node];
  dv = dv > 1.f ? dv : 1.f;
  const float v = xws[i] + agg[i] / dv;
  h[i] = v > 0.f ? v : 0.f;
}

// ---------------- Layer 2 (mu & logstd) + reparameterize ------------------
__global__ __launch_bounds__(256) void k_layer2(
    const float* __restrict__ h, const float* __restrict__ aggh,
    const float* __restrict__ deg, const float* __restrict__ eps,
    const float* __restrict__ Wms, const float* __restrict__ Wmn,
    const float* __restrict__ bm, const float* __restrict__ Wls,
    const float* __restrict__ Wln, const float* __restrict__ bl,
    float* __restrict__ mu_out, float* __restrict__ ls_out,
    float* __restrict__ z) {
  __shared__ float sMs[HID * HID], sMn[HID * HID];
  __shared__ float sLs[HID * HID], sLn[HID * HID];
  __shared__ float sh[8 * HID], shn[8 * HID];
  const int t = threadIdx.x;
  {
    const int i = t * 4;
    *(float4*)&sMs[i] = *(const float4*)&Wms[i];
    *(float4*)&sMn[i] = *(const float4*)&Wmn[i];
    *(float4*)&sLs[i] = *(const float4*)&Wls[i];
    *(float4*)&sLn[i] = *(const float4*)&Wln[i];
  }
  const int node0 = blockIdx.x * 8;
  const int lr = t >> 5;
  const int gnode_ld = node0 + lr;
  if (gnode_ld < N_NODES) {
    float dv = deg[gnode_ld];
    dv = dv > 1.f ? dv : 1.f;
    sh[t] = h[node0 * HID + t];
    shn[t] = aggh[node0 * HID + t] / dv;
  } else {
    sh[t] = 0.f;
    shn[t] = 0.f;
  }
  __syncthreads();
  const int r = t >> 5, c = t & 31;
  const int node = node0 + r;
  float mu = 0.f, ls = 0.f;
  #pragma unroll 8
  for (int k = 0; k < HID; ++k) {
    const float a = sh[r * HID + k];
    const float an = shn[r * HID + k];
    mu += a * sMs[k * HID + c] + an * sMn[k * HID + c];
    ls += a * sLs[k * HID + c] + an * sLn[k * HID + c];
  }
  if (node < N_NODES) {
    mu += bm[c];
    ls += bl[c];
    const int idx = node * HID + c;
    mu_out[idx] = mu;
    ls_out[idx] = ls;
    z[idx] = mu + eps[idx] * __expf(ls);
  }
}

// ---------------- Decoder: adj = sigmoid(z z^T) via bf16 MFMA -------------
// 128x128 tile / 4 waves; wave = 64x64 (4x4 tiles of 16x16).
// LDS: zh/zl for A-rows and B-rows, rows padded to 40 shorts (80 B) ->
// fragment b128 reads are bank-balanced (8-row period covers all 32 banks).
// mfma_f32_16x16x32_bf16: A row=lane&15, k=(lane>>4)*8+e; C/D col=lane&15,
// row=(lane>>4)*4+reg (HW-verified layout).
#define NT 79                         // ceil(10000/128)
#define DNWG (NT * NT)                // 6241
#define DNWG_Q (DNWG / 8)             // 780
#define DNWG_R (DNWG % 8)             // 1
#define ROWP 40                       // LDS row pitch in shorts (80 B)

__global__ __launch_bounds__(256) void k_decode(const float* __restrict__ z,
                                                float* __restrict__ adj) {
  __shared__ short sah[128 * ROWP];
  __shared__ short sal[128 * ROWP];
  __shared__ short sbh[128 * ROWP];
  __shared__ short sbl[128 * ROWP];

  const int bid = blockIdx.x;
  const int xcd = bid & 7, idx = bid >> 3;
  const int wg = (xcd < DNWG_R)
                     ? xcd * (DNWG_Q + 1) + idx
                     : DNWG_R * (DNWG_Q + 1) + (xcd - DNWG_R) * DNWG_Q + idx;
  const int r0 = (wg / NT) * 128;
  const int c0 = (wg % NT) * 128;
  const int t = threadIdx.x;

  // stage: 128 rows x 32 floats per side, converted to bf16 hi/lo
  for (int i = t; i < 1024; i += 256) {
    const int row = i >> 3;
    const int kq = (i & 7) << 2;          // float col 0,4,...,28
    const int gr = r0 + row, gc = c0 + row;
    float4 va = make_float4(0.f, 0.f, 0.f, 0.f);
    float4 vb = make_float4(0.f, 0.f, 0.f, 0.f);
    if (gr < N_NODES) va = *(const float4*)&z[gr * HID + kq];
    if (gc < N_NODES) vb = *(const float4*)&z[gc * HID + kq];
    const float fa[4] = {va.x, va.y, va.z, va.w};
    const float fb[4] = {vb.x, vb.y, vb.z, vb.w};
    short ha[4], la[4], hb[4], lb[4];
    #pragma unroll
    for (int e = 0; e < 4; ++e) {
      unsigned ua = __float_as_uint(fa[e]);
      ha[e] = (short)(ua >> 16);
      float ra = fa[e] - __uint_as_float(ua & 0xFFFF0000u);  // exact
      la[e] = (short)(__float_as_uint(ra) >> 16);
      unsigned ub = __float_as_uint(fb[e]);
      hb[e] = (short)(ub >> 16);
      float rb = fb[e] - __uint_as_float(ub & 0xFFFF0000u);
      lb[e] = (short)(__float_as_uint(rb) >> 16);
    }
    const int off = row * ROWP + kq;
    *(short4*)&sah[off] = make_short4(ha[0], ha[1], ha[2], ha[3]);
    *(short4*)&sal[off] = make_short4(la[0], la[1], la[2], la[3]);
    *(short4*)&sbh[off] = make_short4(hb[0], hb[1], hb[2], hb[3]);
    *(short4*)&sbl[off] = make_short4(lb[0], lb[1], lb[2], lb[3]);
  }
  __syncthreads();

  const int wid = t >> 6;                 // 0..3
  const int lane = t & 63;
  const int wr = (wid >> 1) * 64;         // wave row offset in tile
  const int wc = (wid & 1) * 64;          // wave col offset in tile
  const int lrow = lane & 15;             // A-row / B-col / C-col
  const int lchunk = lane >> 4;           // 0..3: k-chunk, C row group
  const bool interior = (r0 + 128 <= N_NODES) && (c0 + 128 <= N_NODES);

  // B fragments for all 4 col subtiles (live across i loop)
  bf16x8 Bh[4], Bl[4];
  #pragma unroll
  for (int j = 0; j < 4; ++j) {
    const int boff = (wc + j * 16 + lrow) * ROWP + lchunk * 8;
    Bh[j] = *(const bf16x8*)&sbh[boff];
    Bl[j] = *(const bf16x8*)&sbl[boff];
  }

  #pragma unroll
  for (int i = 0; i < 4; ++i) {
    const int aoff = (wr + i * 16 + lrow) * ROWP + lchunk * 8;
    const bf16x8 Ah = *(const bf16x8*)&sah[aoff];
    const bf16x8 Al = *(const bf16x8*)&sal[aoff];
    #pragma unroll
    for (int j = 0; j < 4; ++j) {
      f32x4 acc = {0.f, 0.f, 0.f, 0.f};
      acc = __builtin_amdgcn_mfma_f32_16x16x32_bf16(Ah, Bh[j], acc, 0, 0, 0);
      acc = __builtin_amdgcn_mfma_f32_16x16x32_bf16(Ah, Bl[j], acc, 0, 0, 0);
      acc = __builtin_amdgcn_mfma_f32_16x16x32_bf16(Al, Bh[j], acc, 0, 0, 0);
      const int ccol = c0 + wc + j * 16 + lrow;
      const int rbase = r0 + wr + i * 16 + lchunk * 4;
      if (interior) {
        #pragma unroll
        for (int r = 0; r < 4; ++r) {
          const float s = __builtin_amdgcn_rcpf(1.f + __expf(-acc[r]));
          adj[(size_t)(rbase + r) * N_NODES + ccol] = s;
        }
      } else {
        #pragma unroll
        for (int r = 0; r < 4; ++r) {
          if (rbase + r < N_NODES && ccol < N_NODES) {
            const float s = __builtin_amdgcn_rcpf(1.f + __expf(-acc[r]));
            adj[(size_t)(rbase + r) * N_NODES + ccol] = s;
          }
        }
      }
    }
  }
}

extern "C" void kernel_launch(void* const* d_in, const int* in_sizes, int n_in,
                              void* d_out, int out_size, void* d_ws,
                              size_t ws_size, hipStream_t stream) {
  const float* x   = (const float*)d_in[0];
  const int* src   = (const int*)d_in[1];
  const int* dst   = (const int*)d_in[2];
  const float* eps = (const float*)d_in[3];
  const float* W1s = (const float*)d_in[4];
  const float* W1n = (const float*)d_in[5];
  const float* b1  = (const float*)d_in[6];
  const float* Wms = (const float*)d_in[7];
  const float* Wmn = (const float*)d_in[8];
  const float* bm  = (const float*)d_in[9];
  const float* Wls = (const float*)d_in[10];
  const float* Wln = (const float*)d_in[11];
  const float* bl  = (const float*)d_in[12];

  float* out = (float*)d_out;
  float* adj = out;                                    // [N, N]
  float* mu_out = out + (size_t)N_NODES * N_NODES;     // [N, HID]
  float* ls_out = mu_out + (size_t)N_NODES * HID;      // [N, HID]

  // workspace layout (floats). zeroed region first (deg+agg+aggh).
  float* ws = (float*)d_ws;
  float* deg  = ws;                       // N
  float* agg  = ws + N_NODES;             // N*HID
  float* aggh = agg + N_NODES * HID;      // N*HID
  float* xws  = aggh + N_NODES * HID;     // N*HID
  float* xwn  = xws + N_NODES * HID;      // N*HID
  float* h    = xwn + N_NODES * HID;      // N*HID
  float* z    = h + N_NODES * HID;        // N*HID
  (void)ws_size; (void)in_sizes; (void)n_in; (void)out_size;

  // zero deg + agg + aggh (2.6 MB)
  hipMemsetAsync(ws, 0, (size_t)(N_NODES + 2 * N_NODES * HID) * sizeof(float),
                 stream);

  // layer-1 projections
  k_gemm_in<<<dim3((N_NODES + 31) / 32), dim3(256), 0, stream>>>(
      x, W1s, W1n, b1, xws, xwn);
  // aggregate projected neighbors + degree
  k_aggregate<<<dim3((N_EDGES * HID) / 256), dim3(256), 0, stream>>>(
      xwn, src, dst, agg, deg);
  // h = relu(xws + agg/deg)
  k_layer1_finish<<<dim3((N_NODES * HID) / 256), dim3(256), 0, stream>>>(
      xws, agg, deg, h);
  // aggregate h
  k_aggregate<<<dim3((N_EDGES * HID) / 256), dim3(256), 0, stream>>>(
      h, src, dst, aggh, nullptr);
  // layer 2 + reparameterize
  k_layer2<<<dim3((N_NODES + 7) / 8), dim3(256), 0, stream>>>(
      h, aggh, deg, eps, Wms, Wmn, bm, Wls, Wln, bl, mu_out, ls_out, z);
  // decode (1D grid, XCD-swizzled, MFMA)
  k_decode<<<dim3(DNWG), dim3(256), 0, stream>>>(z, adj);
}

// Round 10
// 555.742 us; speedup vs baseline: 1.5146x; 1.0004x over previous
//
#include <hip/hip_runtime.h>
#include <hip/hip_bf16.h>

// VGAE on MI355X. N=10000, E=320000, F_IN=128, HID=32.
// Round 8 (resubmit x2): hoist the bf16 hi/lo split out of the decode
// staging loop. k_layer2 writes zh/zl (bf16 truncate + exact residual) ONCE
// per element; k_decode stages them with plain 16B loads (round 7
// re-converted each row ~79x inside the tile loop -- ~half of decode's
// cycles were staging VALU). Decode: z.z' = zh.zh' + zh.zl' + zl.zh' via
// mfma_f32_16x16x32_bf16.

#define N_NODES 10000
#define N_EDGES 320000
#define F_IN 128
#define HID 32

typedef short bf16x8 __attribute__((ext_vector_type(8)));
typedef float f32x4 __attribute__((ext_vector_type(4)));

// ---------------- Layer-1 input GEMM: xws = x@W1s + b1, xwn = x@W1n -------
__global__ __launch_bounds__(256) void k_gemm_in(
    const float* __restrict__ x, const float* __restrict__ Ws,
    const float* __restrict__ Wn, const float* __restrict__ b,
    float* __restrict__ outS, float* __restrict__ outN) {
  __shared__ float sWs[F_IN * HID];   // 16 KB
  __shared__ float sWn[F_IN * HID];   // 16 KB
  __shared__ float sx[32 * F_IN];     // 16 KB
  const int t = threadIdx.x;
  const int node0 = blockIdx.x * 32;
  #pragma unroll
  for (int i = t * 4; i < F_IN * HID; i += 1024) {
    *(float4*)&sWs[i] = *(const float4*)&Ws[i];
    *(float4*)&sWn[i] = *(const float4*)&Wn[i];
  }
  #pragma unroll
  for (int i = t * 4; i < 32 * F_IN; i += 1024) {
    const int r = i >> 7, k = i & 127;
    const int gr = node0 + r;
    float4 v = make_float4(0.f, 0.f, 0.f, 0.f);
    if (gr < N_NODES) v = *(const float4*)&x[gr * F_IN + k];
    *(float4*)&sx[i] = v;
  }
  __syncthreads();
  const int c = t & 31, g = t >> 5;
  float accS[4] = {0.f, 0.f, 0.f, 0.f};
  float accN[4] = {0.f, 0.f, 0.f, 0.f};
  #pragma unroll 4
  for (int k = 0; k < F_IN; ++k) {
    const float ws = sWs[k * HID + c];
    const float wn = sWn[k * HID + c];
    #pragma unroll
    for (int m = 0; m < 4; ++m) {
      const float a = sx[(g + 8 * m) * F_IN + k];
      accS[m] += a * ws;
      accN[m] += a * wn;
    }
  }
  const float bc = b[c];
  #pragma unroll
  for (int m = 0; m < 4; ++m) {
    const int node = node0 + g + 8 * m;
    if (node < N_NODES) {
      outS[node * HID + c] = accS[m] + bc;
      outN[node * HID + c] = accN[m];
    }
  }
}

// ---------------- Edge aggregation: agg[dst] += feat[src] (atomics) -------
__global__ __launch_bounds__(256) void k_aggregate(
    const float* __restrict__ feat, const int* __restrict__ src,
    const int* __restrict__ dst, float* __restrict__ agg,
    float* __restrict__ deg) {
  const int tid = blockIdx.x * 256 + threadIdx.x;
  const int e = tid >> 5;
  const int k = tid & 31;
  if (e >= N_EDGES) return;
  const int s = src[e];
  const int d = dst[e];
  atomicAdd(&agg[d * HID + k], feat[s * HID + k]);
  if (deg != nullptr && k == 0) atomicAdd(&deg[d], 1.0f);
}

// ---------------- Layer-1 finish: h = relu(xws + agg/deg) -----------------
__global__ __launch_bounds__(256) void k_layer1_finish(
    const float* __restrict__ xws, const float* __restrict__ agg,
    const float* __restrict__ deg, float* __restrict__ h) {
  const int i = blockIdx.x * 256 + threadIdx.x;
  if (i >= N_NODES * HID) return;
  const int node = i >> 5;
  float dv = deg[node];
  dv = dv > 1.f ? dv : 1.f;
  const float v = xws[i] + agg[i] / dv;
  h[i] = v > 0.f ? v : 0.f;
}

// ---------------- Layer 2 + reparameterize + bf16 hi/lo split -------------
__global__ __launch_bounds__(256) void k_layer2(
    const float* __restrict__ h, const float* __restrict__ aggh,
    const float* __restrict__ deg, const float* __restrict__ eps,
    const float* __restrict__ Wms, const float* __restrict__ Wmn,
    const float* __restrict__ bm, const float* __restrict__ Wls,
    const float* __restrict__ Wln, const float* __restrict__ bl,
    float* __restrict__ mu_out, float* __restrict__ ls_out,
    short* __restrict__ zh, short* __restrict__ zl) {
  __shared__ float sMs[HID * HID], sMn[HID * HID];
  __shared__ float sLs[HID * HID], sLn[HID * HID];
  __shared__ float sh[8 * HID], shn[8 * HID];
  const int t = threadIdx.x;
  {
    const int i = t * 4;
    *(float4*)&sMs[i] = *(const float4*)&Wms[i];
    *(float4*)&sMn[i] = *(const float4*)&Wmn[i];
    *(float4*)&sLs[i] = *(const float4*)&Wls[i];
    *(float4*)&sLn[i] = *(const float4*)&Wln[i];
  }
  const int node0 = blockIdx.x * 8;
  const int lr = t >> 5;
  const int gnode_ld = node0 + lr;
  if (gnode_ld < N_NODES) {
    float dv = deg[gnode_ld];
    dv = dv > 1.f ? dv : 1.f;
    sh[t] = h[node0 * HID + t];
    shn[t] = aggh[node0 * HID + t] / dv;
  } else {
    sh[t] = 0.f;
    shn[t] = 0.f;
  }
  __syncthreads();
  const int r = t >> 5, c = t & 31;
  const int node = node0 + r;
  float mu = 0.f, ls = 0.f;
  #pragma unroll 8
  for (int k = 0; k < HID; ++k) {
    const float a = sh[r * HID + k];
    const float an = shn[r * HID + k];
    mu += a * sMs[k * HID + c] + an * sMn[k * HID + c];
    ls += a * sLs[k * HID + c] + an * sLn[k * HID + c];
  }
  if (node < N_NODES) {
    mu += bm[c];
    ls += bl[c];
    const int idx = node * HID + c;
    mu_out[idx] = mu;
    ls_out[idx] = ls;
    const float zv = mu + eps[idx] * __expf(ls);
    const unsigned u = __float_as_uint(zv);
    zh[idx] = (short)(u >> 16);
    const float res = zv - __uint_as_float(u & 0xFFFF0000u);  // exact
    zl[idx] = (short)(__float_as_uint(res) >> 16);
  }
}

// ---------------- Decoder: adj = sigmoid(z z^T) via bf16 MFMA -------------
// 128x128 tile / 4 waves; wave = 64x64 (4x4 subtiles of 16x16).
// zh/zl precomputed; staging = 8x 16B loads + 8 LDS writes per thread.
// LDS rows padded to 40 shorts (80 B): fragment b128 reads hit all 32 banks
// over the 8-row period -> max 2-way (free).
#define NT 79                         // ceil(10000/128)
#define DNWG (NT * NT)                // 6241
#define DNWG_Q (DNWG / 8)             // 780
#define DNWG_R (DNWG % 8)             // 1
#define ROWP 40                       // LDS row pitch in shorts (80 B)

__global__ __launch_bounds__(256) void k_decode(const short* __restrict__ zh,
                                                const short* __restrict__ zl,
                                                float* __restrict__ adj) {
  __shared__ short sah[128 * ROWP];
  __shared__ short sal[128 * ROWP];
  __shared__ short sbh[128 * ROWP];
  __shared__ short sbl[128 * ROWP];

  const int bid = blockIdx.x;
  const int xcd = bid & 7, idx = bid >> 3;
  const int wg = (xcd < DNWG_R)
                     ? xcd * (DNWG_Q + 1) + idx
                     : DNWG_R * (DNWG_Q + 1) + (xcd - DNWG_R) * DNWG_Q + idx;
  const int r0 = (wg / NT) * 128;
  const int c0 = (wg % NT) * 128;
  const int t = threadIdx.x;

  // stage 4 arrays x 128 rows x 32 shorts (as 4x 8-short chunks)
  #pragma unroll
  for (int i = t; i < 2048; i += 256) {
    const int arr = i >> 9;             // 0:ah 1:al 2:bh 3:bl
    const int rem = i & 511;
    const int row = rem >> 2;
    const int ch = (rem & 3) << 3;      // 0,8,16,24
    const int g = (arr < 2 ? r0 : c0) + row;
    const short* srcp = (arr & 1) ? zl : zh;
    bf16x8 v = {0, 0, 0, 0, 0, 0, 0, 0};
    if (g < N_NODES) v = *(const bf16x8*)&srcp[g * HID + ch];
    short* dstp = (arr == 0) ? sah : (arr == 1) ? sal : (arr == 2) ? sbh : sbl;
    *(bf16x8*)&dstp[row * ROWP + ch] = v;
  }
  __syncthreads();

  const int wid = t >> 6;                 // 0..3
  const int lane = t & 63;
  const int wr = (wid >> 1) * 64;         // wave row offset in tile
  const int wc = (wid & 1) * 64;          // wave col offset in tile
  const int lrow = lane & 15;             // A-row / B-col / C-col
  const int lchunk = lane >> 4;           // k-chunk, C row group
  const bool interior = (r0 + 128 <= N_NODES) && (c0 + 128 <= N_NODES);

  // B fragments for all 4 col subtiles (live across i loop)
  bf16x8 Bh[4], Bl[4];
  #pragma unroll
  for (int j = 0; j < 4; ++j) {
    const int boff = (wc + j * 16 + lrow) * ROWP + lchunk * 8;
    Bh[j] = *(const bf16x8*)&sbh[boff];
    Bl[j] = *(const bf16x8*)&sbl[boff];
  }

  #pragma unroll
  for (int i = 0; i < 4; ++i) {
    const int aoff = (wr + i * 16 + lrow) * ROWP + lchunk * 8;
    const bf16x8 Ah = *(const bf16x8*)&sah[aoff];
    const bf16x8 Al = *(const bf16x8*)&sal[aoff];
    #pragma unroll
    for (int j = 0; j < 4; ++j) {
      f32x4 acc = {0.f, 0.f, 0.f, 0.f};
      acc = __builtin_amdgcn_mfma_f32_16x16x32_bf16(Ah, Bh[j], acc, 0, 0, 0);
      acc = __builtin_amdgcn_mfma_f32_16x16x32_bf16(Ah, Bl[j], acc, 0, 0, 0);
      acc = __builtin_amdgcn_mfma_f32_16x16x32_bf16(Al, Bh[j], acc, 0, 0, 0);
      const int ccol = c0 + wc + j * 16 + lrow;
      const int rbase = r0 + wr + i * 16 + lchunk * 4;
      if (interior) {
        #pragma unroll
        for (int r = 0; r < 4; ++r) {
          const float s = __builtin_amdgcn_rcpf(1.f + __expf(-acc[r]));
          adj[(size_t)(rbase + r) * N_NODES + ccol] = s;
        }
      } else {
        #pragma unroll
        for (int r = 0; r < 4; ++r) {
          if (rbase + r < N_NODES && ccol < N_NODES) {
            const float s = __builtin_amdgcn_rcpf(1.f + __expf(-acc[r]));
            adj[(size_t)(rbase + r) * N_NODES + ccol] = s;
          }
        }
      }
    }
  }
}

extern "C" void kernel_launch(void* const* d_in, const int* in_sizes, int n_in,
                              void* d_out, int out_size, void* d_ws,
                              size_t ws_size, hipStream_t stream) {
  const float* x   = (const float*)d_in[0];
  const int* src   = (const int*)d_in[1];
  const int* dst   = (const int*)d_in[2];
  const float* eps = (const float*)d_in[3];
  const float* W1s = (const float*)d_in[4];
  const float* W1n = (const float*)d_in[5];
  const float* b1  = (const float*)d_in[6];
  const float* Wms = (const float*)d_in[7];
  const float* Wmn = (const float*)d_in[8];
  const float* bm  = (const float*)d_in[9];
  const float* Wls = (const float*)d_in[10];
  const float* Wln = (const float*)d_in[11];
  const float* bl  = (const float*)d_in[12];

  float* out = (float*)d_out;
  float* adj = out;                                    // [N, N]
  float* mu_out = out + (size_t)N_NODES * N_NODES;     // [N, HID]
  float* ls_out = mu_out + (size_t)N_NODES * HID;      // [N, HID]

  // workspace layout (floats). zeroed region first (deg+agg+aggh).
  float* ws = (float*)d_ws;
  float* deg  = ws;                       // N
  float* agg  = ws + N_NODES;             // N*HID
  float* aggh = agg + N_NODES * HID;      // N*HID
  float* xws  = aggh + N_NODES * HID;     // N*HID
  float* xwn  = xws + N_NODES * HID;      // N*HID
  float* h    = xwn + N_NODES * HID;      // N*HID
  short* zh   = (short*)(h + N_NODES * HID);           // N*HID bf16
  short* zl   = zh + N_NODES * HID;                    // N*HID bf16
  (void)ws_size; (void)in_sizes; (void)n_in; (void)out_size;

  // zero deg + agg + aggh (2.6 MB)
  hipMemsetAsync(ws, 0, (size_t)(N_NODES + 2 * N_NODES * HID) * sizeof(float),
                 stream);

  // layer-1 projections
  k_gemm_in<<<dim3((N_NODES + 31) / 32), dim3(256), 0, stream>>>(
      x, W1s, W1n, b1, xws, xwn);
  // aggregate projected neighbors + degree
  k_aggregate<<<dim3((N_EDGES * HID) / 256), dim3(256), 0, stream>>>(
      xwn, src, dst, agg, deg);
  // h = relu(xws + agg/deg)
  k_layer1_finish<<<dim3((N_NODES * HID) / 256), dim3(256), 0, stream>>>(
      xws, agg, deg, h);
  // aggregate h
  k_aggregate<<<dim3((N_EDGES * HID) / 256), dim3(256), 0, stream>>>(
      h, src, dst, aggh, nullptr);
  // layer 2 + reparameterize + split
  k_layer2<<<dim3((N_NODES + 7) / 8), dim3(256), 0, stream>>>(
      h, aggh, deg, eps, Wms, Wmn, bm, Wls, Wln, bl, mu_out, ls_out, zh, zl);
  // decode (1D grid, XCD-swizzled, MFMA on precomputed zh/zl)
  k_decode<<<dim3(DNWG), dim3(256), 0, stream>>>(zh, zl, adj);
}